// Round 5
// baseline (164.611 us; speedup 1.0000x reference)
//
#include <hip/hip_runtime.h>
#include <math.h>

#define NL 8
#define NH 2048
#define NO 1000
#define ROWS 4   // rows per block in kernel A

__device__ __forceinline__ float dot4(float4 a, float4 b) {
    return a.x * b.x + a.y * b.y + a.z * b.z + a.w * b.w;
}

__device__ __forceinline__ float wave_sum(float v) {
#pragma unroll
    for (int off = 32; off > 0; off >>= 1) v += __shfl_xor(v, off);
    return v;
}

// Kernel A: one block (6 waves = 6 gates) per ROWS consecutive rows of one
// layer. Vector chunks live in registers and are reused across all rows;
// weight regs are scoped per row so the allocator reuses them (R2 lesson:
// never pin min-occupancy; R3 lesson: don't fight the allocator with
// rotation). Demand path is ~96% saturated; this trims L1/addressing work.
__global__ __launch_bounds__(384) void gru_gates_kernel(
    const float* __restrict__ x,    // [NH]
    const float* __restrict__ h,    // [NL, NH]
    const float* __restrict__ W_ir, const float* __restrict__ b_ir,
    const float* __restrict__ W_hr, const float* __restrict__ b_hr,
    const float* __restrict__ W_h1, const float* __restrict__ b_h1,
    const float* __restrict__ W_x1, const float* __restrict__ b_x1,
    const float* __restrict__ W_iu, const float* __restrict__ b_iu,
    const float* __restrict__ W_hu, const float* __restrict__ b_hu,
    float* __restrict__ new_h)      // [NL, NH]  (== d_out + NO)
{
    const int row0 = blockIdx.x * ROWS;   // global row index l*NH + r0
    const int l    = row0 >> 11;          // / NH  (ROWS divides NH -> same layer)
    const int g    = threadIdx.x >> 6;    // gate id 0..5 (wave-uniform)
    const int lane = threadIdx.x & 63;

    __shared__ float part[ROWS][6];

    const float* vi = (l == 0) ? x : (h + (size_t)(l - 1) * NH);
    const float* vh = h + (size_t)l * NH;
    const float* __restrict__ W;
    const float* __restrict__ bv;
    const float* vecf;
    switch (g) {
        case 0:  W = W_ir; bv = b_ir; vecf = vi; break;
        case 1:  W = W_hr; bv = b_hr; vecf = vh; break;
        case 2:  W = W_h1; bv = b_h1; vecf = vh; break;
        case 3:  W = W_x1; bv = b_x1; vecf = vi; break;
        case 4:  W = W_iu; bv = b_iu; vecf = vi; break;
        default: W = W_hu; bv = b_hu; vecf = vh; break;
    }
    const float4* __restrict__ vec = (const float4*)vecf;

    // Vector chunks: loaded once, reused for all ROWS rows (32 VGPR).
    const float4 v0 = vec[lane +   0];
    const float4 v1 = vec[lane +  64];
    const float4 v2 = vec[lane + 128];
    const float4 v3 = vec[lane + 192];
    const float4 v4 = vec[lane + 256];
    const float4 v5 = vec[lane + 320];
    const float4 v6 = vec[lane + 384];
    const float4 v7 = vec[lane + 448];

    const float4* __restrict__ wrow = (const float4*)(W + (size_t)row0 * NH);

    float s0, s1, s2, s3;
    {
        const float4* __restrict__ wr = wrow;
        const float4 w0 = wr[lane +   0], w1 = wr[lane +  64];
        const float4 w2 = wr[lane + 128], w3 = wr[lane + 192];
        const float4 w4 = wr[lane + 256], w5 = wr[lane + 320];
        const float4 w6 = wr[lane + 384], w7 = wr[lane + 448];
        s0 = dot4(v0,w0)+dot4(v1,w1)+dot4(v2,w2)+dot4(v3,w3)
           + dot4(v4,w4)+dot4(v5,w5)+dot4(v6,w6)+dot4(v7,w7);
    }
    {
        const float4* __restrict__ wr = wrow + (NH / 4);
        const float4 w0 = wr[lane +   0], w1 = wr[lane +  64];
        const float4 w2 = wr[lane + 128], w3 = wr[lane + 192];
        const float4 w4 = wr[lane + 256], w5 = wr[lane + 320];
        const float4 w6 = wr[lane + 384], w7 = wr[lane + 448];
        s1 = dot4(v0,w0)+dot4(v1,w1)+dot4(v2,w2)+dot4(v3,w3)
           + dot4(v4,w4)+dot4(v5,w5)+dot4(v6,w6)+dot4(v7,w7);
    }
    {
        const float4* __restrict__ wr = wrow + 2 * (NH / 4);
        const float4 w0 = wr[lane +   0], w1 = wr[lane +  64];
        const float4 w2 = wr[lane + 128], w3 = wr[lane + 192];
        const float4 w4 = wr[lane + 256], w5 = wr[lane + 320];
        const float4 w6 = wr[lane + 384], w7 = wr[lane + 448];
        s2 = dot4(v0,w0)+dot4(v1,w1)+dot4(v2,w2)+dot4(v3,w3)
           + dot4(v4,w4)+dot4(v5,w5)+dot4(v6,w6)+dot4(v7,w7);
    }
    {
        const float4* __restrict__ wr = wrow + 3 * (NH / 4);
        const float4 w0 = wr[lane +   0], w1 = wr[lane +  64];
        const float4 w2 = wr[lane + 128], w3 = wr[lane + 192];
        const float4 w4 = wr[lane + 256], w5 = wr[lane + 320];
        const float4 w6 = wr[lane + 384], w7 = wr[lane + 448];
        s3 = dot4(v0,w0)+dot4(v1,w1)+dot4(v2,w2)+dot4(v3,w3)
           + dot4(v4,w4)+dot4(v5,w5)+dot4(v6,w6)+dot4(v7,w7);
    }

    // Deferred reductions: load stream above is uninterrupted by shuffles.
    s0 = wave_sum(s0);
    s1 = wave_sum(s1);
    s2 = wave_sum(s2);
    s3 = wave_sum(s3);
    if (lane == 0) {
        part[0][g] = s0 + bv[row0 + 0];
        part[1][g] = s1 + bv[row0 + 1];
        part[2][g] = s2 + bv[row0 + 2];
        part[3][g] = s3 + bv[row0 + 3];
    }
    __syncthreads();

    if (threadIdx.x < ROWS) {
        const int r  = threadIdx.x;
        const int bi = row0 + r;
        const float reset = 1.f / (1.f + expf(-(part[r][0] + part[r][1])));
        const float rr    = tanhf(reset * part[r][2] + part[r][3]);
        const float u     = 1.f / (1.f + expf(-(part[r][4] + part[r][5])));
        new_h[bi] = (1.f - u) * rr + u * h[bi];
    }
}

// Kernel B+C fused: FC GEMV (one wave per output row), then the LAST block
// (elected via device-scope atomic counter) computes the log-softmax.
// Producer: store logits -> __threadfence -> sync -> atomicAdd (release).
// Consumer: sees final count -> __threadfence (acquire) -> reads logits.
__global__ __launch_bounds__(256) void fc_lsm_kernel(
    const float* __restrict__ new_h,   // [NL, NH]
    const float* __restrict__ W_fc,    // [NO, NH]
    const float* __restrict__ b_fc,    // [NO]
    float* __restrict__ logits,        // [NO] (workspace)
    unsigned int* __restrict__ counter,
    float* __restrict__ out)           // [NO] log-softmax
{
    const int lane = threadIdx.x & 63;
    const int wid  = threadIdx.x >> 6;
    const int row  = blockIdx.x * 4 + wid;

    if (row < NO) {
        const float4* __restrict__ v  = (const float4*)(new_h + (size_t)(NL - 1) * NH);
        const float4* __restrict__ wt = (const float4*)(W_fc + (size_t)row * NH);
        float s = 0.f;
#pragma unroll
        for (int c = 0; c < 8; ++c) {
            const int k = c * 64 + lane;
            float4 vv = v[k];
            vv.x = fmaxf(vv.x, 0.f); vv.y = fmaxf(vv.y, 0.f);
            vv.z = fmaxf(vv.z, 0.f); vv.w = fmaxf(vv.w, 0.f);
            s += dot4(vv, wt[k]);
        }
        s = wave_sum(s);
        if (lane == 0) logits[row] = s + b_fc[row];
    }
    __threadfence();
    __syncthreads();

    __shared__ unsigned int lastflag;
    if (threadIdx.x == 0)
        lastflag = (atomicAdd(counter, 1u) == gridDim.x - 1) ? 1u : 0u;
    __syncthreads();
    if (!lastflag) return;
    __threadfence();

    // ---- last block: log-softmax over logits[0..NO) with 256 threads ----
    const int t = threadIdx.x;
    float l0 = -INFINITY, l1 = -INFINITY, l2 = -INFINITY, l3 = -INFINITY;
    if (t       < NO) l0 = logits[t];
    if (t + 256 < NO) l1 = logits[t + 256];
    if (t + 512 < NO) l2 = logits[t + 512];
    if (t + 768 < NO) l3 = logits[t + 768];

    __shared__ float redm[4];
    float m = fmaxf(fmaxf(l0, l1), fmaxf(l2, l3));
#pragma unroll
    for (int off = 32; off > 0; off >>= 1) m = fmaxf(m, __shfl_xor(m, off));
    if (lane == 0) redm[wid] = m;
    __syncthreads();
    m = fmaxf(fmaxf(redm[0], redm[1]), fmaxf(redm[2], redm[3]));

    __shared__ float reds[4];
    float e = 0.f;
    if (t       < NO) e += expf(l0 - m);
    if (t + 256 < NO) e += expf(l1 - m);
    if (t + 512 < NO) e += expf(l2 - m);
    if (t + 768 < NO) e += expf(l3 - m);
#pragma unroll
    for (int off = 32; off > 0; off >>= 1) e += __shfl_xor(e, off);
    if (lane == 0) reds[wid] = e;
    __syncthreads();
    const float lse = m + logf(reds[0] + reds[1] + reds[2] + reds[3]);

    if (t       < NO) out[t]       = l0 - lse;
    if (t + 256 < NO) out[t + 256] = l1 - lse;
    if (t + 512 < NO) out[t + 512] = l2 - lse;
    if (t + 768 < NO) out[t + 768] = l3 - lse;
}

extern "C" void kernel_launch(void* const* d_in, const int* in_sizes, int n_in,
                              void* d_out, int out_size, void* d_ws, size_t ws_size,
                              hipStream_t stream) {
    const float* x    = (const float*)d_in[0];
    const float* h    = (const float*)d_in[1];
    const float* W_ir = (const float*)d_in[2];
    const float* b_ir = (const float*)d_in[3];
    const float* W_hr = (const float*)d_in[4];
    const float* b_hr = (const float*)d_in[5];
    const float* W_h1 = (const float*)d_in[6];
    const float* b_h1 = (const float*)d_in[7];
    const float* W_x1 = (const float*)d_in[8];
    const float* b_x1 = (const float*)d_in[9];
    const float* W_iu = (const float*)d_in[10];
    const float* b_iu = (const float*)d_in[11];
    const float* W_hu = (const float*)d_in[12];
    const float* b_hu = (const float*)d_in[13];
    const float* W_fc = (const float*)d_in[14];
    const float* b_fc = (const float*)d_in[15];

    float* out    = (float*)d_out;              // [NO] log-softmax output
    float* new_h  = out + NO;                   // [NL*NH] second tuple element
    float* logits = (float*)d_ws;               // [NO] scratch
    unsigned int* counter = (unsigned int*)((char*)d_ws + 4096);

    // Zero the election counter (capture-legal async memset, stream-ordered).
    hipMemsetAsync(counter, 0, sizeof(unsigned int), stream);

    // Kernel A: one block per ROWS rows; 6 waves = 6 gates.
    gru_gates_kernel<<<(NL * NH) / ROWS, 384, 0, stream>>>(
        x, h, W_ir, b_ir, W_hr, b_hr, W_h1, b_h1, W_x1, b_x1,
        W_iu, b_iu, W_hu, b_hu, new_h);

    // Kernel B+C fused: 250 blocks x 4 waves; last block does log-softmax.
    fc_lsm_kernel<<<(NO + 3) / 4, 256, 0, stream>>>(
        new_h, W_fc, b_fc, logits, counter, out);
}

// Round 6
// 160.519 us; speedup vs baseline: 1.0255x; 1.0255x over previous
//
#include <hip/hip_runtime.h>
#include <math.h>

#define NL 8
#define NH 2048
#define NO 1000

__device__ __forceinline__ float dot4(float4 a, float4 b) {
    return a.x * b.x + a.y * b.y + a.z * b.z + a.w * b.w;
}

__device__ __forceinline__ float wave_sum(float v) {
#pragma unroll
    for (int off = 32; off > 0; off >>= 1) v += __shfl_xor(v, off);
    return v;
}

// Kernel A (R4 form — best measured): one block (384 thr = 6 waves) per
// (layer,row); one wave per gate. Each wave streams ONE 8KB weight row via
// 8 independent float4 loads. Measured: ~6.0 TB/s demand (~96% of the
// 6.3 TB/s per-CU vector-return ceiling), occupancy ~50%, VGPR 36.
// R5 lesson: ROWS>1 lengthens live ranges and serializes row streams -> worse.
__global__ __launch_bounds__(384) void gru_gates_kernel(
    const float* __restrict__ x,    // [NH]
    const float* __restrict__ h,    // [NL, NH]
    const float* __restrict__ W_ir, const float* __restrict__ b_ir,
    const float* __restrict__ W_hr, const float* __restrict__ b_hr,
    const float* __restrict__ W_h1, const float* __restrict__ b_h1,
    const float* __restrict__ W_x1, const float* __restrict__ b_x1,
    const float* __restrict__ W_iu, const float* __restrict__ b_iu,
    const float* __restrict__ W_hu, const float* __restrict__ b_hu,
    float* __restrict__ new_h)      // [NL, NH]  (== d_out + NO)
{
    const int bi   = blockIdx.x;          // 0 .. NL*NH-1  == l*NH + row
    const int l    = bi >> 11;            // / NH
    const int g    = threadIdx.x >> 6;    // gate id 0..5 (wave-uniform)
    const int lane = threadIdx.x & 63;

    __shared__ float part[6];

    // gate -> (weight matrix, bias, input vector)
    // 0:ir(vi) 1:hr(vh) 2:h1(vh) 3:x1(vi) 4:iu(vi) 5:hu(vh)
    const float* __restrict__ W;
    const float* __restrict__ bv;
    const float* vecf;
    const float* vi = (l == 0) ? x : (h + (size_t)(l - 1) * NH);
    const float* vh = h + (size_t)l * NH;
    switch (g) {
        case 0:  W = W_ir; bv = b_ir; vecf = vi; break;
        case 1:  W = W_hr; bv = b_hr; vecf = vh; break;
        case 2:  W = W_h1; bv = b_h1; vecf = vh; break;
        case 3:  W = W_x1; bv = b_x1; vecf = vi; break;
        case 4:  W = W_iu; bv = b_iu; vecf = vi; break;
        default: W = W_hu; bv = b_hu; vecf = vh; break;
    }
    const float4* __restrict__ wrow = (const float4*)(W + (size_t)bi * NH);
    const float4* __restrict__ vec  = (const float4*)vecf;

    // Issue all 8 weight loads first (independent regs -> deep in flight);
    // vector chunks are L1/L2-hot and interleave with the dots.
    const float4 w0 = wrow[lane +   0];
    const float4 w1 = wrow[lane +  64];
    const float4 w2 = wrow[lane + 128];
    const float4 w3 = wrow[lane + 192];
    const float4 w4 = wrow[lane + 256];
    const float4 w5 = wrow[lane + 320];
    const float4 w6 = wrow[lane + 384];
    const float4 w7 = wrow[lane + 448];

    float s;
    s  = dot4(vec[lane +   0], w0);
    s += dot4(vec[lane +  64], w1);
    s += dot4(vec[lane + 128], w2);
    s += dot4(vec[lane + 192], w3);
    s += dot4(vec[lane + 256], w4);
    s += dot4(vec[lane + 320], w5);
    s += dot4(vec[lane + 384], w6);
    s += dot4(vec[lane + 448], w7);

    s = wave_sum(s);
    if (lane == 0) part[g] = s + bv[bi];
    __syncthreads();

    if (threadIdx.x == 0) {
        const float reset = 1.f / (1.f + expf(-(part[0] + part[1])));
        const float r     = tanhf(reset * part[2] + part[3]);
        const float u     = 1.f / (1.f + expf(-(part[4] + part[5])));
        const float hv    = h[bi];
        new_h[bi] = (1.f - u) * r + u * hv;
    }
}

// Kernel B+C fused: FC GEMV (one wave per output row), then the LAST block
// (elected via device-scope atomic counter) computes the log-softmax.
__global__ __launch_bounds__(256) void fc_lsm_kernel(
    const float* __restrict__ new_h,   // [NL, NH]
    const float* __restrict__ W_fc,    // [NO, NH]
    const float* __restrict__ b_fc,    // [NO]
    float* __restrict__ logits,        // [NO] (workspace)
    unsigned int* __restrict__ counter,
    float* __restrict__ out)           // [NO] log-softmax
{
    const int lane = threadIdx.x & 63;
    const int wid  = threadIdx.x >> 6;
    const int row  = blockIdx.x * 4 + wid;

    if (row < NO) {
        const float4* __restrict__ v  = (const float4*)(new_h + (size_t)(NL - 1) * NH);
        const float4* __restrict__ wt = (const float4*)(W_fc + (size_t)row * NH);
        float s = 0.f;
#pragma unroll
        for (int c = 0; c < 8; ++c) {
            const int k = c * 64 + lane;
            float4 vv = v[k];
            vv.x = fmaxf(vv.x, 0.f); vv.y = fmaxf(vv.y, 0.f);
            vv.z = fmaxf(vv.z, 0.f); vv.w = fmaxf(vv.w, 0.f);
            s += dot4(vv, wt[k]);
        }
        s = wave_sum(s);
        if (lane == 0) logits[row] = s + b_fc[row];
    }
    __threadfence();
    __syncthreads();

    __shared__ unsigned int lastflag;
    if (threadIdx.x == 0)
        lastflag = (atomicAdd(counter, 1u) == gridDim.x - 1) ? 1u : 0u;
    __syncthreads();
    if (!lastflag) return;
    __threadfence();

    // ---- last block: log-softmax over logits[0..NO) with 256 threads ----
    const int t = threadIdx.x;
    float l0 = -INFINITY, l1 = -INFINITY, l2 = -INFINITY, l3 = -INFINITY;
    if (t       < NO) l0 = logits[t];
    if (t + 256 < NO) l1 = logits[t + 256];
    if (t + 512 < NO) l2 = logits[t + 512];
    if (t + 768 < NO) l3 = logits[t + 768];

    __shared__ float redm[4];
    float m = fmaxf(fmaxf(l0, l1), fmaxf(l2, l3));
#pragma unroll
    for (int off = 32; off > 0; off >>= 1) m = fmaxf(m, __shfl_xor(m, off));
    if (lane == 0) redm[wid] = m;
    __syncthreads();
    m = fmaxf(fmaxf(redm[0], redm[1]), fmaxf(redm[2], redm[3]));

    __shared__ float reds[4];
    float e = 0.f;
    if (t       < NO) e += expf(l0 - m);
    if (t + 256 < NO) e += expf(l1 - m);
    if (t + 512 < NO) e += expf(l2 - m);
    if (t + 768 < NO) e += expf(l3 - m);
#pragma unroll
    for (int off = 32; off > 0; off >>= 1) e += __shfl_xor(e, off);
    if (lane == 0) reds[wid] = e;
    __syncthreads();
    const float lse = m + logf(reds[0] + reds[1] + reds[2] + reds[3]);

    if (t       < NO) out[t]       = l0 - lse;
    if (t + 256 < NO) out[t + 256] = l1 - lse;
    if (t + 512 < NO) out[t + 512] = l2 - lse;
    if (t + 768 < NO) out[t + 768] = l3 - lse;
}

extern "C" void kernel_launch(void* const* d_in, const int* in_sizes, int n_in,
                              void* d_out, int out_size, void* d_ws, size_t ws_size,
                              hipStream_t stream) {
    const float* x    = (const float*)d_in[0];
    const float* h    = (const float*)d_in[1];
    const float* W_ir = (const float*)d_in[2];
    const float* b_ir = (const float*)d_in[3];
    const float* W_hr = (const float*)d_in[4];
    const float* b_hr = (const float*)d_in[5];
    const float* W_h1 = (const float*)d_in[6];
    const float* b_h1 = (const float*)d_in[7];
    const float* W_x1 = (const float*)d_in[8];
    const float* b_x1 = (const float*)d_in[9];
    const float* W_iu = (const float*)d_in[10];
    const float* b_iu = (const float*)d_in[11];
    const float* W_hu = (const float*)d_in[12];
    const float* b_hu = (const float*)d_in[13];
    const float* W_fc = (const float*)d_in[14];
    const float* b_fc = (const float*)d_in[15];

    float* out    = (float*)d_out;              // [NO] log-softmax output
    float* new_h  = out + NO;                   // [NL*NH] second tuple element
    float* logits = (float*)d_ws;               // [NO] scratch
    unsigned int* counter = (unsigned int*)((char*)d_ws + 4096);

    // Zero the election counter (capture-legal async memset, stream-ordered).
    hipMemsetAsync(counter, 0, sizeof(unsigned int), stream);

    // Kernel A: one block per (layer,row); 6 waves = 6 gates.
    gru_gates_kernel<<<NL * NH, 384, 0, stream>>>(
        x, h, W_ir, b_ir, W_hr, b_hr, W_h1, b_h1, W_x1, b_x1,
        W_iu, b_iu, W_hu, b_hu, new_h);

    // Kernel B+C fused: 250 blocks x 4 waves; last block does log-softmax.
    fc_lsm_kernel<<<(NO + 3) / 4, 256, 0, stream>>>(
        new_h, W_fc, b_fc, logits, counter, out);
}

// Round 7
// 140.827 us; speedup vs baseline: 1.1689x; 1.1398x over previous
//
#include <hip/hip_runtime.h>
#include <math.h>

#define NL 8
#define NH 2048
#define NO 1000

__device__ __forceinline__ float dot4(float4 a, float4 b) {
    return a.x * b.x + a.y * b.y + a.z * b.z + a.w * b.w;
}

__device__ __forceinline__ float4 relu4(float4 a) {
    return make_float4(fmaxf(a.x, 0.f), fmaxf(a.y, 0.f), fmaxf(a.z, 0.f), fmaxf(a.w, 0.f));
}

__device__ __forceinline__ float wave_sum(float v) {
#pragma unroll
    for (int off = 32; off > 0; off >>= 1) v += __shfl_xor(v, off);
    return v;
}

// Kernel A (best measured — R4): one block (384 thr = 6 waves) per
// (layer,row); one wave per gate. Each wave streams ONE 8KB weight row via
// 8 independent float4 loads. Measured: ~6.0 TB/s demand (~96% of the
// 6.29 TB/s m13 copy ceiling), occupancy ~50%, VGPR 36.
// R5 lesson: ROWS>1 serializes row streams. R6 lesson: atomic-election
// fusion of the tail costs ~18us in device fences -> keep separate kernels.
__global__ __launch_bounds__(384) void gru_gates_kernel(
    const float* __restrict__ x,    // [NH]
    const float* __restrict__ h,    // [NL, NH]
    const float* __restrict__ W_ir, const float* __restrict__ b_ir,
    const float* __restrict__ W_hr, const float* __restrict__ b_hr,
    const float* __restrict__ W_h1, const float* __restrict__ b_h1,
    const float* __restrict__ W_x1, const float* __restrict__ b_x1,
    const float* __restrict__ W_iu, const float* __restrict__ b_iu,
    const float* __restrict__ W_hu, const float* __restrict__ b_hu,
    float* __restrict__ new_h)      // [NL, NH]  (== d_out + NO)
{
    const int bi   = blockIdx.x;          // 0 .. NL*NH-1  == l*NH + row
    const int l    = bi >> 11;            // / NH
    const int g    = threadIdx.x >> 6;    // gate id 0..5 (wave-uniform)
    const int lane = threadIdx.x & 63;

    __shared__ float part[6];

    // gate -> (weight matrix, bias, input vector)
    // 0:ir(vi) 1:hr(vh) 2:h1(vh) 3:x1(vi) 4:iu(vi) 5:hu(vh)
    const float* __restrict__ W;
    const float* __restrict__ bv;
    const float* vecf;
    const float* vi = (l == 0) ? x : (h + (size_t)(l - 1) * NH);
    const float* vh = h + (size_t)l * NH;
    switch (g) {
        case 0:  W = W_ir; bv = b_ir; vecf = vi; break;
        case 1:  W = W_hr; bv = b_hr; vecf = vh; break;
        case 2:  W = W_h1; bv = b_h1; vecf = vh; break;
        case 3:  W = W_x1; bv = b_x1; vecf = vi; break;
        case 4:  W = W_iu; bv = b_iu; vecf = vi; break;
        default: W = W_hu; bv = b_hu; vecf = vh; break;
    }
    const float4* __restrict__ wrow = (const float4*)(W + (size_t)bi * NH);
    const float4* __restrict__ vec  = (const float4*)vecf;

    // Issue all 8 weight loads first (independent regs -> deep in flight);
    // vector chunks are L1/L2-hot and interleave with the dots.
    const float4 w0 = wrow[lane +   0];
    const float4 w1 = wrow[lane +  64];
    const float4 w2 = wrow[lane + 128];
    const float4 w3 = wrow[lane + 192];
    const float4 w4 = wrow[lane + 256];
    const float4 w5 = wrow[lane + 320];
    const float4 w6 = wrow[lane + 384];
    const float4 w7 = wrow[lane + 448];

    float s;
    s  = dot4(vec[lane +   0], w0);
    s += dot4(vec[lane +  64], w1);
    s += dot4(vec[lane + 128], w2);
    s += dot4(vec[lane + 192], w3);
    s += dot4(vec[lane + 256], w4);
    s += dot4(vec[lane + 320], w5);
    s += dot4(vec[lane + 384], w6);
    s += dot4(vec[lane + 448], w7);

    s = wave_sum(s);
    if (lane == 0) part[g] = s + bv[bi];
    __syncthreads();

    if (threadIdx.x == 0) {
        const float reset = 1.f / (1.f + expf(-(part[0] + part[1])));
        const float r     = tanhf(reset * part[2] + part[3]);
        const float u     = 1.f / (1.f + expf(-(part[4] + part[5])));
        const float hv    = h[bi];
        new_h[bi] = (1.f - u) * r + u * hv;
    }
}

// Kernel B: FC GEMV on relu(new_h[last]). One wave per output row.
__global__ __launch_bounds__(256) void fc_kernel(
    const float* __restrict__ new_h,  // [NL, NH]
    const float* __restrict__ W_fc,   // [NO, NH]
    const float* __restrict__ b_fc,   // [NO]
    float* __restrict__ logits)       // [NO] (workspace)
{
    const int wave = (blockIdx.x * blockDim.x + threadIdx.x) >> 6;
    const int lane = threadIdx.x & 63;
    if (wave >= NO) return;
    const float4* __restrict__ v = (const float4*)(new_h + (size_t)(NL - 1) * NH);
    const float4* __restrict__ w = (const float4*)(W_fc + (size_t)wave * NH);
    float s = 0.f;
#pragma unroll
    for (int it = 0; it < NH / 4 / 64 / 2; ++it) {
        const int k0 = it * 128 + lane;
        const int k1 = k0 + 64;
        const float4 v0 = v[k0];
        const float4 w0 = w[k0];
        const float4 v1 = v[k1];
        const float4 w1 = w[k1];
        s += dot4(relu4(v0), w0) + dot4(relu4(v1), w1);
    }
    s = wave_sum(s);
    if (lane == 0) logits[wave] = s + b_fc[wave];
}

// Kernel C: log_softmax over NO=1000 elements, single block of 1024.
__global__ __launch_bounds__(1024) void lsm_kernel(
    const float* __restrict__ logits, float* __restrict__ out)
{
    const int t = threadIdx.x;
    const int lane = t & 63;
    const int wid = t >> 6;
    __shared__ float sred[16];

    const float v = (t < NO) ? logits[t] : -INFINITY;

    // block max
    float m = v;
#pragma unroll
    for (int off = 32; off > 0; off >>= 1) m = fmaxf(m, __shfl_xor(m, off));
    if (lane == 0) sred[wid] = m;
    __syncthreads();
    if (wid == 0) {
        float mm = (t < 16) ? sred[t] : -INFINITY;
#pragma unroll
        for (int off = 8; off > 0; off >>= 1) mm = fmaxf(mm, __shfl_xor(mm, off));
        if (t == 0) sred[0] = mm;
    }
    __syncthreads();
    const float M = sred[0];
    __syncthreads();

    // block sum of exp
    float e = (t < NO) ? expf(v - M) : 0.f;
    float s = e;
#pragma unroll
    for (int off = 32; off > 0; off >>= 1) s += __shfl_xor(s, off);
    if (lane == 0) sred[wid] = s;
    __syncthreads();
    if (wid == 0) {
        float ss = (t < 16) ? sred[t] : 0.f;
#pragma unroll
        for (int off = 8; off > 0; off >>= 1) ss += __shfl_xor(ss, off);
        if (t == 0) sred[0] = ss;
    }
    __syncthreads();
    const float lse = M + logf(sred[0]);

    if (t < NO) out[t] = v - lse;
}

extern "C" void kernel_launch(void* const* d_in, const int* in_sizes, int n_in,
                              void* d_out, int out_size, void* d_ws, size_t ws_size,
                              hipStream_t stream) {
    const float* x    = (const float*)d_in[0];
    const float* h    = (const float*)d_in[1];
    const float* W_ir = (const float*)d_in[2];
    const float* b_ir = (const float*)d_in[3];
    const float* W_hr = (const float*)d_in[4];
    const float* b_hr = (const float*)d_in[5];
    const float* W_h1 = (const float*)d_in[6];
    const float* b_h1 = (const float*)d_in[7];
    const float* W_x1 = (const float*)d_in[8];
    const float* b_x1 = (const float*)d_in[9];
    const float* W_iu = (const float*)d_in[10];
    const float* b_iu = (const float*)d_in[11];
    const float* W_hu = (const float*)d_in[12];
    const float* b_hu = (const float*)d_in[13];
    const float* W_fc = (const float*)d_in[14];
    const float* b_fc = (const float*)d_in[15];

    float* out    = (float*)d_out;      // [NO] log-softmax output
    float* new_h  = out + NO;           // [NL*NH] second tuple element
    float* logits = (float*)d_ws;       // [NO] scratch

    // Kernel A: one block per (layer,row); 6 waves = 6 gates.
    gru_gates_kernel<<<NL * NH, 384, 0, stream>>>(
        x, h, W_ir, b_ir, W_hr, b_hr, W_h1, b_h1, W_x1, b_x1,
        W_iu, b_iu, W_hu, b_hu, new_h);

    // Kernel B: NO waves, 4 waves per block -> 250 blocks.
    fc_kernel<<<(NO + 3) / 4, 256, 0, stream>>>(new_h, W_fc, b_fc, logits);

    // Kernel C: single block log-softmax.
    lsm_kernel<<<1, 1024, 0, stream>>>(logits, out);
}

// Round 8
// 139.128 us; speedup vs baseline: 1.1832x; 1.0122x over previous
//
#include <hip/hip_runtime.h>
#include <math.h>

#define NL 8
#define NH 2048
#define NO 1000

__device__ __forceinline__ float dot4(float4 a, float4 b) {
    return a.x * b.x + a.y * b.y + a.z * b.z + a.w * b.w;
}

__device__ __forceinline__ float4 relu4(float4 a) {
    return make_float4(fmaxf(a.x, 0.f), fmaxf(a.y, 0.f), fmaxf(a.z, 0.f), fmaxf(a.w, 0.f));
}

__device__ __forceinline__ float wave_sum(float v) {
#pragma unroll
    for (int off = 32; off > 0; off >>= 1) v += __shfl_xor(v, off);
    return v;
}

// Kernel A: gate-per-wave (R4 structure) + LDS vector staging.
// Theory under test: the per-CU VMEM *return* path is the binding resource
// (R4 moved 13.6 B/cyc/CU through it: 805MB weight misses + 805MB L1-hit
// vector re-reads). Staging vi/vh into LDS once per block cuts per-block
// VMEM return 96KB -> 64KB; dots then feed from the separate LDS pipe.
// Weight loads are issued BEFORE staging so they are in flight throughout.
__global__ __launch_bounds__(384) void gru_gates_kernel(
    const float* __restrict__ x,    // [NH]
    const float* __restrict__ h,    // [NL, NH]
    const float* __restrict__ W_ir, const float* __restrict__ b_ir,
    const float* __restrict__ W_hr, const float* __restrict__ b_hr,
    const float* __restrict__ W_h1, const float* __restrict__ b_h1,
    const float* __restrict__ W_x1, const float* __restrict__ b_x1,
    const float* __restrict__ W_iu, const float* __restrict__ b_iu,
    const float* __restrict__ W_hu, const float* __restrict__ b_hu,
    float* __restrict__ new_h)      // [NL, NH]  (== d_out + NO)
{
    const int bi   = blockIdx.x;          // 0 .. NL*NH-1  == l*NH + row
    const int l    = bi >> 11;            // / NH
    const int g    = threadIdx.x >> 6;    // gate id 0..5 (wave-uniform)
    const int lane = threadIdx.x & 63;

    __shared__ float4 svec[1024];         // [0:512) = vi, [512:1024) = vh (16 KB)
    __shared__ float part[6];

    const float* vi = (l == 0) ? x : (h + (size_t)(l - 1) * NH);
    const float* vh = h + (size_t)l * NH;

    // gate -> (weight matrix, bias, vector half in LDS)
    // 0:ir(vi) 1:hr(vh) 2:h1(vh) 3:x1(vi) 4:iu(vi) 5:hu(vh)
    const float* __restrict__ W;
    const float* __restrict__ bv;
    int voff;
    switch (g) {
        case 0:  W = W_ir; bv = b_ir; voff = 0;   break;
        case 1:  W = W_hr; bv = b_hr; voff = 512; break;
        case 2:  W = W_h1; bv = b_h1; voff = 512; break;
        case 3:  W = W_x1; bv = b_x1; voff = 0;   break;
        case 4:  W = W_iu; bv = b_iu; voff = 0;   break;
        default: W = W_hu; bv = b_hu; voff = 512; break;
    }
    const float4* __restrict__ wrow = (const float4*)(W + (size_t)bi * NH);

    // ---- issue all 8 weight loads first (in flight across staging+barrier) ----
    const float4 w0 = wrow[lane +   0];
    const float4 w1 = wrow[lane +  64];
    const float4 w2 = wrow[lane + 128];
    const float4 w3 = wrow[lane + 192];
    const float4 w4 = wrow[lane + 256];
    const float4 w5 = wrow[lane + 320];
    const float4 w6 = wrow[lane + 384];
    const float4 w7 = wrow[lane + 448];

    // ---- cooperative staging of vi,vh into LDS (L1/L2-hot, 16 KB) ----
    const float4* __restrict__ gvi = (const float4*)vi;
    const float4* __restrict__ gvh = (const float4*)vh;
    {
        const int t = threadIdx.x;
        svec[t] = gvi[t];
        if (t < 128) svec[384 + t] = gvi[384 + t];
        svec[512 + t] = gvh[t];
        if (t < 128) svec[896 + t] = gvh[384 + t];
    }
    __syncthreads();

    const float4* __restrict__ vs = svec + voff;
    float s;
    s  = dot4(vs[lane +   0], w0);
    s += dot4(vs[lane +  64], w1);
    s += dot4(vs[lane + 128], w2);
    s += dot4(vs[lane + 192], w3);
    s += dot4(vs[lane + 256], w4);
    s += dot4(vs[lane + 320], w5);
    s += dot4(vs[lane + 384], w6);
    s += dot4(vs[lane + 448], w7);

    s = wave_sum(s);
    if (lane == 0) part[g] = s + bv[bi];
    __syncthreads();

    if (threadIdx.x == 0) {
        const float reset = 1.f / (1.f + expf(-(part[0] + part[1])));
        const float r     = tanhf(reset * part[2] + part[3]);
        const float u     = 1.f / (1.f + expf(-(part[4] + part[5])));
        const float hv    = h[bi];
        new_h[bi] = (1.f - u) * r + u * hv;
    }
}

// Kernel B: FC GEMV on relu(new_h[last]). One wave per output row.
__global__ __launch_bounds__(256) void fc_kernel(
    const float* __restrict__ new_h,  // [NL, NH]
    const float* __restrict__ W_fc,   // [NO, NH]
    const float* __restrict__ b_fc,   // [NO]
    float* __restrict__ logits)       // [NO] (workspace)
{
    const int wave = (blockIdx.x * blockDim.x + threadIdx.x) >> 6;
    const int lane = threadIdx.x & 63;
    if (wave >= NO) return;
    const float4* __restrict__ v = (const float4*)(new_h + (size_t)(NL - 1) * NH);
    const float4* __restrict__ w = (const float4*)(W_fc + (size_t)wave * NH);
    float s = 0.f;
#pragma unroll
    for (int it = 0; it < NH / 4 / 64 / 2; ++it) {
        const int k0 = it * 128 + lane;
        const int k1 = k0 + 64;
        const float4 v0 = v[k0];
        const float4 w0 = w[k0];
        const float4 v1 = v[k1];
        const float4 w1 = w[k1];
        s += dot4(relu4(v0), w0) + dot4(relu4(v1), w1);
    }
    s = wave_sum(s);
    if (lane == 0) logits[wave] = s + b_fc[wave];
}

// Kernel C: log_softmax over NO=1000 elements, single block of 1024.
__global__ __launch_bounds__(1024) void lsm_kernel(
    const float* __restrict__ logits, float* __restrict__ out)
{
    const int t = threadIdx.x;
    const int lane = t & 63;
    const int wid = t >> 6;
    __shared__ float sred[16];

    const float v = (t < NO) ? logits[t] : -INFINITY;

    // block max
    float m = v;
#pragma unroll
    for (int off = 32; off > 0; off >>= 1) m = fmaxf(m, __shfl_xor(m, off));
    if (lane == 0) sred[wid] = m;
    __syncthreads();
    if (wid == 0) {
        float mm = (t < 16) ? sred[t] : -INFINITY;
#pragma unroll
        for (int off = 8; off > 0; off >>= 1) mm = fmaxf(mm, __shfl_xor(mm, off));
        if (t == 0) sred[0] = mm;
    }
    __syncthreads();
    const float M = sred[0];
    __syncthreads();

    // block sum of exp
    float e = (t < NO) ? expf(v - M) : 0.f;
    float s = e;
#pragma unroll
    for (int off = 32; off > 0; off >>= 1) s += __shfl_xor(s, off);
    if (lane == 0) sred[wid] = s;
    __syncthreads();
    if (wid == 0) {
        float ss = (t < 16) ? sred[t] : 0.f;
#pragma unroll
        for (int off = 8; off > 0; off >>= 1) ss += __shfl_xor(ss, off);
        if (t == 0) sred[0] = ss;
    }
    __syncthreads();
    const float lse = M + logf(sred[0]);

    if (t < NO) out[t] = v - lse;
}

extern "C" void kernel_launch(void* const* d_in, const int* in_sizes, int n_in,
                              void* d_out, int out_size, void* d_ws, size_t ws_size,
                              hipStream_t stream) {
    const float* x    = (const float*)d_in[0];
    const float* h    = (const float*)d_in[1];
    const float* W_ir = (const float*)d_in[2];
    const float* b_ir = (const float*)d_in[3];
    const float* W_hr = (const float*)d_in[4];
    const float* b_hr = (const float*)d_in[5];
    const float* W_h1 = (const float*)d_in[6];
    const float* b_h1 = (const float*)d_in[7];
    const float* W_x1 = (const float*)d_in[8];
    const float* b_x1 = (const float*)d_in[9];
    const float* W_iu = (const float*)d_in[10];
    const float* b_iu = (const float*)d_in[11];
    const float* W_hu = (const float*)d_in[12];
    const float* b_hu = (const float*)d_in[13];
    const float* W_fc = (const float*)d_in[14];
    const float* b_fc = (const float*)d_in[15];

    float* out    = (float*)d_out;      // [NO] log-softmax output
    float* new_h  = out + NO;           // [NL*NH] second tuple element
    float* logits = (float*)d_ws;       // [NO] scratch

    // Kernel A: one block per (layer,row); 6 waves = 6 gates; LDS-staged vectors.
    gru_gates_kernel<<<NL * NH, 384, 0, stream>>>(
        x, h, W_ir, b_ir, W_hr, b_hr, W_h1, b_h1, W_x1, b_x1,
        W_iu, b_iu, W_hu, b_hu, new_h);

    // Kernel B: NO waves, 4 waves per block -> 250 blocks.
    fc_kernel<<<(NO + 3) / 4, 256, 0, stream>>>(new_h, W_fc, b_fc, logits);

    // Kernel C: single block log-softmax.
    lsm_kernel<<<1, 1024, 0, stream>>>(logits, out);
}